// Round 3
// baseline (137.249 us; speedup 1.0000x reference)
//
#include <hip/hip_runtime.h>
#include <hip/hip_bf16.h>
#include <stdint.h>

#define B_ROWS 8192
#define HDIM   1024
#define IDIM   128
#define KDIM   1152
#define TMAX   128

typedef unsigned short u16;
typedef __bf16 bf16x8 __attribute__((ext_vector_type(8)));
typedef float  f32x4  __attribute__((ext_vector_type(4)));

static __device__ __forceinline__ u16 f2bf(float f) {
  union { float f; unsigned u; } v; v.f = f;
  unsigned r = v.u + 0x7FFFu + ((v.u >> 16) & 1u);
  return (u16)(r >> 16);
}
static __device__ __forceinline__ float bf2f(u16 b) {
  union { unsigned u; float f; } v; v.u = ((unsigned)b) << 16; return v.f;
}

template<int N> __device__ __forceinline__ void waitv() {
  if constexpr (N == 8)      asm volatile("s_waitcnt vmcnt(8)" ::: "memory");
  else if constexpr (N == 6) asm volatile("s_waitcnt vmcnt(6)" ::: "memory");
  else if constexpr (N == 4) asm volatile("s_waitcnt vmcnt(4)" ::: "memory");
  else if constexpr (N == 3) asm volatile("s_waitcnt vmcnt(3)" ::: "memory");
  else                       asm volatile("s_waitcnt vmcnt(0)" ::: "memory");
}

// ---------------------------------------------------------------------------
// Kernel 1: bf16 conversion/staging (unchanged, verified)
// ---------------------------------------------------------------------------
#define W_CHUNKS  (3*1024*1152/4)
#define H_CHUNKS  (B_ROWS*HDIM/4)
#define X_CHUNKS  (B_ROWS*IDIM/4)
#define W_BLOCKS  (W_CHUNKS/256)
#define H_BLOCKS  (H_CHUNKS/256)
#define X_BLOCKS  (X_CHUNKS/256)
#define CV_BLOCKS (W_BLOCKS + H_BLOCKS + X_BLOCKS)

__global__ __launch_bounds__(256)
void convert_kernel(const float* __restrict__ t,
                    const float* __restrict__ h,
                    const float* __restrict__ xc,
                    const float* __restrict__ Wr,
                    const float* __restrict__ Wz,
                    const float* __restrict__ Wh,
                    u16* __restrict__ WB,
                    u16* __restrict__ A1,
                    u16* __restrict__ A2)
{
  const int b = blockIdx.x;
  const int tid = threadIdx.x;
  if (b < W_BLOCKS) {
    const int g = b * 256 + tid;
    const int e = g * 4;
    const int S = 1024 * KDIM;
    float4 v;
    if (e < S)            v = *reinterpret_cast<const float4*>(Wr + e);
    else if (e < 2 * S)   v = *reinterpret_cast<const float4*>(Wz + (e - S));
    else                  v = *reinterpret_cast<const float4*>(Wh + (e - 2 * S));
    ushort4 o; o.x = f2bf(v.x); o.y = f2bf(v.y); o.z = f2bf(v.z); o.w = f2bf(v.w);
    *reinterpret_cast<ushort4*>(WB + e) = o;
  } else if (b < W_BLOCKS + H_BLOCKS) {
    const int g = (b - W_BLOCKS) * 256 + tid;
    const int e = g * 4;
    const int row = e >> 10, col = e & 1023;
    float4 v = *reinterpret_cast<const float4*>(h + e);
    ushort4 o; o.x = f2bf(v.x); o.y = f2bf(v.y); o.z = f2bf(v.z); o.w = f2bf(v.w);
    *reinterpret_cast<ushort4*>(A1 + (size_t)row * KDIM + IDIM + col) = o;
  } else {
    const int g = (b - W_BLOCKS - H_BLOCKS) * 256 + tid;
    const int e = g * 4;
    int ti = (int)t[0];
    ti = ti < 0 ? 0 : (ti > TMAX - 1 ? TMAX - 1 : ti);
    const int row = e >> 7, col = e & 127;
    float4 v = *reinterpret_cast<const float4*>(xc + (size_t)ti * B_ROWS * IDIM + e);
    ushort4 o; o.x = f2bf(v.x); o.y = f2bf(v.y); o.z = f2bf(v.z); o.w = f2bf(v.w);
    *reinterpret_cast<ushort4*>(A1 + (size_t)row * KDIM + col) = o;
    *reinterpret_cast<ushort4*>(A2 + (size_t)row * KDIM + col) = o;
  }
}

// ---------------------------------------------------------------------------
// 8-phase 256-wide GEMM (m201 template port). C[m][n] = sum_k A[m][k]*W[n][k].
// BM=256, BK=64, 512 threads (8 waves, 2M x 4N), interleaved-half wave map:
// wave (wm,wn) owns rows {mh*128 + wm*64 + 0..63} x cols {nh*(BN/2) + wn*WNS + ...}.
// Each phase: 1 quadrant (mh,nh) x K=64 -> reads exactly A-half mh, B-half nh.
// dbuf x half LDS; 1 half-tile staged per phase into the slot freed last phase;
// counted vmcnt(LA+LB) only at phases 4 & 8 (before trailing barrier).
// ---------------------------------------------------------------------------
template<int MODE, int BN, int NTOT>
__global__ __launch_bounds__(512, 2)
void gemm8p(const u16* __restrict__ A, const u16* __restrict__ W,
            const u16* __restrict__ hb, u16* __restrict__ A2w,
            u16* __restrict__ omz, float* __restrict__ out)
{
  constexpr int NBN = NTOT / BN;
  constexpr int NFQ = BN / 128;          // n-frags per quadrant (2 or 1)
  constexpr int WNS = (BN == 256 ? 32 : 16);
  constexpr int LA  = 2;                 // gloads/thread per A-half
  constexpr int LB  = BN / 128;          // gloads/thread per B-half
  constexpr int NT  = KDIM / 64;         // 18 K-tiles
  constexpr int NITER = NT / 2;          // 9

  __shared__ u16 As[2][2][128 * 64];
  __shared__ u16 Bs[2][2][(BN / 2) * 64];

  const int tid  = threadIdx.x;
  const int lane = tid & 63;
  const int wave = tid >> 6;
  const int wm = wave >> 2, wn = wave & 3;
  const int raw = blockIdx.x;                       // 256 blocks, %8==0
  const int swz = (raw & 7) * 32 + (raw >> 3);      // bijective XCD swizzle
  const int bm = swz / NBN, bn = swz % NBN;
  const int rowBase = bm * 256, colBase = bn * BN;
  const int lr = lane & 15, lkq = lane >> 4;

  auto stageA = [&](int buf, int half, int kt) {
    const int k0 = kt * 64;
    #pragma unroll
    for (int rr = 0; rr < LA; ++rr) {
      const int q = rr * 512 + tid;                 // 1024 chunks per A-half
      const int row = q >> 3, cl = q & 7;
      const int cg = cl ^ (row & 7);                // inverse-swizzled source
      const u16* g = A + (size_t)(rowBase + half * 128 + row) * KDIM + k0 + cg * 8;
      __builtin_amdgcn_global_load_lds(
          (const __attribute__((address_space(1))) void*)g,
          (__attribute__((address_space(3))) void*)(&As[buf][half][q * 8]), 16, 0, 0);
    }
  };
  auto stageB = [&](int buf, int half, int kt) {
    const int k0 = kt * 64;
    #pragma unroll
    for (int rr = 0; rr < LB; ++rr) {
      const int q = rr * 512 + tid;                 // (BN/2)*8 chunks per B-half
      const int row = q >> 3, cl = q & 7;
      const int cg = cl ^ (row & 7);
      const u16* g = W + (size_t)(colBase + half * (BN / 2) + row) * KDIM + k0 + cg * 8;
      __builtin_amdgcn_global_load_lds(
          (const __attribute__((address_space(1))) void*)g,
          (__attribute__((address_space(3))) void*)(&Bs[buf][half][q * 8]), 16, 0, 0);
    }
  };

  f32x4 acc[2][2][4][NFQ];
  f32x4 zero = {0.f, 0.f, 0.f, 0.f};
  #pragma unroll
  for (int a = 0; a < 2; ++a)
    #pragma unroll
    for (int b = 0; b < 2; ++b)
      #pragma unroll
      for (int c = 0; c < 4; ++c)
        #pragma unroll
        for (int d = 0; d < NFQ; ++d) acc[a][b][c][d] = zero;

// One phase: ds-read frags | stage | barrier | lgkmcnt(0) | setprio+MFMA | wait | barrier
#define PHASE(T01, MH, NH, STAGE_CODE, WAIT_CODE)  do {                          \
    bf16x8 af[4][2]; bf16x8 bv[NFQ][2];                                          \
    _Pragma("unroll") for (int mf = 0; mf < 4; ++mf) {                           \
      const int r = wm * 64 + mf * 16 + lr;                                      \
      _Pragma("unroll") for (int kk = 0; kk < 2; ++kk) {                         \
        const int c = (kk * 4 + lkq) ^ (r & 7);                                  \
        af[mf][kk] = *reinterpret_cast<const bf16x8*>(&As[T01][MH][r * 64 + c * 8]); \
      } }                                                                        \
    _Pragma("unroll") for (int nf = 0; nf < NFQ; ++nf) {                         \
      const int r = wn * WNS + nf * 16 + lr;                                     \
      _Pragma("unroll") for (int kk = 0; kk < 2; ++kk) {                         \
        const int c = (kk * 4 + lkq) ^ (r & 7);                                  \
        bv[nf][kk] = *reinterpret_cast<const bf16x8*>(&Bs[T01][NH][r * 64 + c * 8]); \
      } }                                                                        \
    STAGE_CODE;                                                                  \
    __builtin_amdgcn_s_barrier();                                                \
    asm volatile("s_waitcnt lgkmcnt(0)" ::: "memory");                           \
    __builtin_amdgcn_s_setprio(1);                                               \
    _Pragma("unroll") for (int mf = 0; mf < 4; ++mf)                             \
      _Pragma("unroll") for (int nf = 0; nf < NFQ; ++nf)                         \
        _Pragma("unroll") for (int kk = 0; kk < 2; ++kk)                         \
          acc[MH][NH][mf][nf] = __builtin_amdgcn_mfma_f32_16x16x32_bf16(         \
              af[mf][kk], bv[nf][kk], acc[MH][NH][mf][nf], 0, 0, 0);             \
    __builtin_amdgcn_s_setprio(0);                                               \
    WAIT_CODE;                                                                   \
    __builtin_amdgcn_s_barrier();                                                \
  } while (0)

  // Prologue: tile0 (all 4 halves) + tile1 halves A0,B0; allow newest LA+LB in flight.
  stageA(0, 0, 0); stageB(0, 0, 0); stageA(0, 1, 0); stageB(0, 1, 0);
  stageA(1, 0, 1); stageB(1, 0, 1);
  waitv<LA + LB>();
  __builtin_amdgcn_s_barrier();

  for (int i = 0; i < NITER; ++i) {
    const int t0 = 2 * i;
    const bool more = (i < NITER - 1);
    // tile t0 (buf0): quadrants (0,0),(1,0),(0,1),(1,1)
    PHASE(0, 0, 0, { stageA(1, 1, t0 + 1); stageB(1, 1, t0 + 1); }, {});
    PHASE(0, 1, 0, {}, {});
    PHASE(0, 0, 1, { if (more) stageB(0, 0, t0 + 2); }, {});
    PHASE(0, 1, 1, { if (more) stageA(0, 0, t0 + 2); },
                   { if (more) waitv<LA + LB>(); else waitv<0>(); });
    // tile t0+1 (buf1)
    PHASE(1, 0, 0, { if (more) { stageA(0, 1, t0 + 2); stageB(0, 1, t0 + 2); } }, {});
    PHASE(1, 1, 0, {}, {});
    PHASE(1, 0, 1, { if (more) stageB(1, 0, t0 + 3); }, {});
    PHASE(1, 1, 1, { if (more) stageA(1, 0, t0 + 3); },
                   { if (more) waitv<LA + LB>(); else waitv<0>(); });
  }
#undef PHASE

  // ---- epilogue: C/D frag layout col=lr, row=lkq*4+rr ----
  #pragma unroll
  for (int mh = 0; mh < 2; ++mh) {
    #pragma unroll
    for (int nh = 0; nh < 2; ++nh) {
      #pragma unroll
      for (int mf = 0; mf < 4; ++mf) {
        #pragma unroll
        for (int nf = 0; nf < NFQ; ++nf) {
          f32x4 v = acc[mh][nh][mf][nf];
          const int col = colBase + nh * (BN / 2) + wn * WNS + nf * 16 + lr;
          #pragma unroll
          for (int rr = 0; rr < 4; ++rr) {
            const int row = rowBase + mh * 128 + wm * 64 + mf * 16 + lkq * 4 + rr;
            const float x = v[rr];
            if (MODE == 0) {
              const float sg = 1.f / (1.f + __expf(-x));
              if (col < HDIM) {
                const float hv = bf2f(hb[(size_t)row * KDIM + IDIM + col]);
                A2w[(size_t)row * KDIM + IDIM + col] = f2bf(sg * hv);
              } else {
                omz[(size_t)row * HDIM + (col - HDIM)] = f2bf(1.f - sg);
              }
            } else {
              const float e  = __expf(2.f * x);
              const float ht = 1.f - 2.f / (e + 1.f);
              const float o  = bf2f(omz[(size_t)row * HDIM + col]);
              const float hv = bf2f(hb[(size_t)row * KDIM + IDIM + col]);
              out[(size_t)row * HDIM + col] = o * (ht - hv);
            }
          }
        }
      }
    }
  }
}

// ---------------------------------------------------------------------------
extern "C" void kernel_launch(void* const* d_in, const int* in_sizes, int n_in,
                              void* d_out, int out_size, void* d_ws, size_t ws_size,
                              hipStream_t stream) {
  const float* t  = (const float*)d_in[0];
  const float* h  = (const float*)d_in[1];
  const float* xc = (const float*)d_in[2];
  const float* Wr = (const float*)d_in[3];
  const float* Wz = (const float*)d_in[4];
  const float* Wh = (const float*)d_in[5];
  float* out = (float*)d_out;

  u16* WB  = (u16*)d_ws;
  u16* A1  = WB + (size_t)3 * 1024 * KDIM;
  u16* A2  = A1 + (size_t)B_ROWS * KDIM;
  u16* omz = A2 + (size_t)B_ROWS * KDIM;

  convert_kernel<<<CV_BLOCKS, 256, 0, stream>>>(t, h, xc, Wr, Wz, Wh, WB, A1, A2);

  // GEMM1: [x|h] x [W_r;W_z]^T ; 32x8 = 256 blocks (BM=256, BN=256)
  gemm8p<0, 256, 2048><<<256, 512, 0, stream>>>(A1, WB, A1, A2, omz, out);

  // GEMM2: [x|r*h] x W_h^T ; 32x8 = 256 blocks (BM=256, BN=128)
  gemm8p<1, 128, 1024><<<256, 512, 0, stream>>>(A2, WB + (size_t)2048 * KDIM,
                                                A1, nullptr, omz, out);
}

// Round 5
// 91.358 us; speedup vs baseline: 1.5023x; 1.5023x over previous
//
#include <hip/hip_runtime.h>
#include <hip/hip_bf16.h>
#include <stdint.h>

#define B_ROWS 8192
#define HDIM   1024
#define IDIM   128
#define KDIM   1152
#define TMAX   128

typedef unsigned short u16;
typedef __bf16 bf16x8 __attribute__((ext_vector_type(8)));
typedef float  f32x4  __attribute__((ext_vector_type(4)));

static __device__ __forceinline__ u16 f2bf(float f) {
  union { float f; unsigned u; } v; v.f = f;
  unsigned r = v.u + 0x7FFFu + ((v.u >> 16) & 1u);
  return (u16)(r >> 16);
}
static __device__ __forceinline__ float bf2f(u16 b) {
  union { unsigned u; float f; } v; v.u = ((unsigned)b) << 16; return v.f;
}

template<int N> __device__ __forceinline__ void waitv() {
  if constexpr (N == 8)      asm volatile("s_waitcnt vmcnt(8)" ::: "memory");
  else if constexpr (N == 6) asm volatile("s_waitcnt vmcnt(6)" ::: "memory");
  else if constexpr (N == 2) asm volatile("s_waitcnt vmcnt(2)" ::: "memory");
  else                       asm volatile("s_waitcnt vmcnt(0)" ::: "memory");
}

// ---------------------------------------------------------------------------
// Kernel 1: bf16 conversion/staging (unchanged, verified)
// ---------------------------------------------------------------------------
#define W_CHUNKS  (3*1024*1152/4)
#define H_CHUNKS  (B_ROWS*HDIM/4)
#define X_CHUNKS  (B_ROWS*IDIM/4)
#define W_BLOCKS  (W_CHUNKS/256)
#define H_BLOCKS  (H_CHUNKS/256)
#define X_BLOCKS  (X_CHUNKS/256)
#define CV_BLOCKS (W_BLOCKS + H_BLOCKS + X_BLOCKS)

__global__ __launch_bounds__(256)
void convert_kernel(const float* __restrict__ t,
                    const float* __restrict__ h,
                    const float* __restrict__ xc,
                    const float* __restrict__ Wr,
                    const float* __restrict__ Wz,
                    const float* __restrict__ Wh,
                    u16* __restrict__ WB,
                    u16* __restrict__ A1,
                    u16* __restrict__ A2)
{
  const int b = blockIdx.x;
  const int tid = threadIdx.x;
  if (b < W_BLOCKS) {
    const int g = b * 256 + tid;
    const int e = g * 4;
    const int S = 1024 * KDIM;
    float4 v;
    if (e < S)            v = *reinterpret_cast<const float4*>(Wr + e);
    else if (e < 2 * S)   v = *reinterpret_cast<const float4*>(Wz + (e - S));
    else                  v = *reinterpret_cast<const float4*>(Wh + (e - 2 * S));
    ushort4 o; o.x = f2bf(v.x); o.y = f2bf(v.y); o.z = f2bf(v.z); o.w = f2bf(v.w);
    *reinterpret_cast<ushort4*>(WB + e) = o;
  } else if (b < W_BLOCKS + H_BLOCKS) {
    const int g = (b - W_BLOCKS) * 256 + tid;
    const int e = g * 4;
    const int row = e >> 10, col = e & 1023;
    float4 v = *reinterpret_cast<const float4*>(h + e);
    ushort4 o; o.x = f2bf(v.x); o.y = f2bf(v.y); o.z = f2bf(v.z); o.w = f2bf(v.w);
    *reinterpret_cast<ushort4*>(A1 + (size_t)row * KDIM + IDIM + col) = o;
  } else {
    const int g = (b - W_BLOCKS - H_BLOCKS) * 256 + tid;
    const int e = g * 4;
    int ti = (int)t[0];
    ti = ti < 0 ? 0 : (ti > TMAX - 1 ? TMAX - 1 : ti);
    const int row = e >> 7, col = e & 127;
    float4 v = *reinterpret_cast<const float4*>(xc + (size_t)ti * B_ROWS * IDIM + e);
    ushort4 o; o.x = f2bf(v.x); o.y = f2bf(v.y); o.z = f2bf(v.z); o.w = f2bf(v.w);
    *reinterpret_cast<ushort4*>(A1 + (size_t)row * KDIM + col) = o;
    *reinterpret_cast<ushort4*>(A2 + (size_t)row * KDIM + col) = o;
  }
}

// ---------------------------------------------------------------------------
// 128x128-tile pipelined GEMM, 4 waves (2x2), 64 KB LDS -> 2 blocks/CU.
// 2 phases per K-tile(64), held B-fragments, 16 b128 reads/K-tile (minimum).
// Counted vmcnt(8) at phase ends (T4); T2 chunk-XOR swizzle both sides;
// T5 setprio. FIX vs round 4: rdA/rdB index rows WITHIN the half sub-tile
// (the half offset was applied twice -> OOB LDS reads -> NaN).
// ---------------------------------------------------------------------------
template<int MODE, int NTOT>
__global__ __launch_bounds__(256, 2)
void gemm128(const u16* __restrict__ A, const u16* __restrict__ W,
             const u16* __restrict__ hb, u16* __restrict__ A2w,
             u16* __restrict__ omz, float* __restrict__ out)
{
  constexpr int NBN = NTOT / 128;
  constexpr int CPB = (B_ROWS / 128) * NBN / 8;   // blocks per XCD
  constexpr int NT  = KDIM / 64;                  // 18 K-tiles

  __shared__ u16 As[2][2][64 * 64];
  __shared__ u16 Bs[2][2][64 * 64];

  const int tid  = threadIdx.x;
  const int lane = tid & 63;
  const int wave = tid >> 6;
  const int wm = wave >> 1, wn = wave & 1;
  const int xcd = blockIdx.x & 7, jj = blockIdx.x >> 3;
  const int virt = xcd * CPB + jj;                // contiguous tiles per XCD
  const int bm = virt / NBN, bn = virt % NBN;
  const int rowBase = bm * 128, colBase = bn * 128;
  const int lr = lane & 15, lkq = lane >> 4;

  auto stA = [&](int buf, int half, int kt) {
    #pragma unroll
    for (int rr = 0; rr < 2; ++rr) {
      const int q = rr * 256 + tid;               // 512 chunks per 64x64 half
      const int row = q >> 3, cl = q & 7;
      const int cg = cl ^ (row & 7);              // inverse-swizzled source
      const u16* g = A + (size_t)(rowBase + half * 64 + row) * KDIM + kt * 64 + cg * 8;
      __builtin_amdgcn_global_load_lds(
          (const __attribute__((address_space(1))) void*)g,
          (__attribute__((address_space(3))) void*)(&As[buf][half][q * 8]), 16, 0, 0);
    }
  };
  auto stB = [&](int buf, int half, int kt) {
    #pragma unroll
    for (int rr = 0; rr < 2; ++rr) {
      const int q = rr * 256 + tid;
      const int row = q >> 3, cl = q & 7;
      const int cg = cl ^ (row & 7);
      const u16* g = W + (size_t)(colBase + half * 64 + row) * KDIM + kt * 64 + cg * 8;
      __builtin_amdgcn_global_load_lds(
          (const __attribute__((address_space(1))) void*)g,
          (__attribute__((address_space(3))) void*)(&Bs[buf][half][q * 8]), 16, 0, 0);
    }
  };

  f32x4 acc[2][2][2][2];                          // [mh][nh][mf][nf]
  f32x4 zero = {0.f, 0.f, 0.f, 0.f};
  #pragma unroll
  for (int a = 0; a < 2; ++a)
    #pragma unroll
    for (int b = 0; b < 2; ++b)
      #pragma unroll
      for (int c = 0; c < 2; ++c)
        #pragma unroll
        for (int d = 0; d < 2; ++d) acc[a][b][c][d] = zero;

  bf16x8 bv[2][2][2];                             // [nh][nf][kk], held PA->PB
  bf16x8 af[2][2];                                // [mf][kk], per-phase

  auto rdA = [&](int buf, int half) {
    #pragma unroll
    for (int mf = 0; mf < 2; ++mf)
      #pragma unroll
      for (int kk = 0; kk < 2; ++kk) {
        const int r = wm * 32 + mf * 16 + lr;     // row WITHIN half (FIX)
        const int c = (kk * 4 + lkq) ^ (r & 7);
        af[mf][kk] = *reinterpret_cast<const bf16x8*>(&As[buf][half][r * 64 + c * 8]);
      }
  };
  auto rdB = [&](int buf) {
    #pragma unroll
    for (int nh = 0; nh < 2; ++nh)
      #pragma unroll
      for (int nf = 0; nf < 2; ++nf)
        #pragma unroll
        for (int kk = 0; kk < 2; ++kk) {
          const int r = wn * 32 + nf * 16 + lr;   // row WITHIN half (FIX)
          const int c = (kk * 4 + lkq) ^ (r & 7);
          bv[nh][nf][kk] = *reinterpret_cast<const bf16x8*>(&Bs[buf][nh][r * 64 + c * 8]);
        }
  };

#define MFMA_QUAD(MH, NH)                                                       \
    _Pragma("unroll") for (int mf = 0; mf < 2; ++mf)                            \
      _Pragma("unroll") for (int nf = 0; nf < 2; ++nf)                          \
        _Pragma("unroll") for (int kk = 0; kk < 2; ++kk)                        \
          acc[MH][NH][mf][nf] = __builtin_amdgcn_mfma_f32_16x16x32_bf16(        \
              af[mf][kk], bv[NH][nf][kk], acc[MH][NH][mf][nf], 0, 0, 0);

#define PHASE_A(BUF, T, DO_STAGE, WV)  do {                                     \
    rdA(BUF, 0); rdB(BUF);                                                      \
    if (DO_STAGE) stA((BUF) ^ 1, 1, (T) + 1);       /* A1(t+1) */               \
    __builtin_amdgcn_s_barrier();                                               \
    asm volatile("s_waitcnt lgkmcnt(0)" ::: "memory");                          \
    __builtin_amdgcn_s_setprio(1);                                              \
    MFMA_QUAD(0, 0); MFMA_QUAD(0, 1);                                           \
    __builtin_amdgcn_s_setprio(0);                                              \
    waitv<WV>();                                                                \
    __builtin_amdgcn_s_barrier();                                               \
  } while (0)

#define PHASE_B(BUF, T, DO_STAGE, WV)  do {                                     \
    rdA(BUF, 1);                                                                \
    if (DO_STAGE) { stA(BUF, 0, (T) + 2); stB(BUF, 0, (T) + 2);                 \
                    stB(BUF, 1, (T) + 2); }                                     \
    __builtin_amdgcn_s_barrier();                                               \
    asm volatile("s_waitcnt lgkmcnt(0)" ::: "memory");                          \
    __builtin_amdgcn_s_setprio(1);                                              \
    MFMA_QUAD(1, 1); MFMA_QUAD(1, 0);                                           \
    __builtin_amdgcn_s_setprio(0);                                              \
    waitv<WV>();                                                                \
    __builtin_amdgcn_s_barrier();                                               \
  } while (0)

  // Prologue: tile0 all 4 halves (8 loads), tile1 A0,B0,B1 (6 loads).
  stA(0, 0, 0); stB(0, 0, 0); stB(0, 1, 0); stA(0, 1, 0);
  stA(1, 0, 1); stB(1, 0, 1); stB(1, 1, 1);
  waitv<6>();                                     // tile0 fully landed
  __builtin_amdgcn_s_barrier();

  // Main loop: t = 0..15 full pipeline (NT=18).
  for (int t = 0; t < NT - 2; ++t) {
    const int buf = t & 1;
    PHASE_A(buf, t, true, 8);
    PHASE_B(buf, t, true, 8);
  }
  // t = 16: PA stages A1(17); PB stages nothing, drain to 2 (leave A1(17)).
  PHASE_A(0, 16, true, 8);
  PHASE_B(0, 16, false, 2);
  // t = 17: no stages; PA drains A1(17) before PB reads it.
  PHASE_A(1, 17, false, 0);
  PHASE_B(1, 17, false, 0);

#undef PHASE_A
#undef PHASE_B
#undef MFMA_QUAD

  // ---- epilogue: C/D layout col=lr, row=lkq*4+rr ----
  if (MODE == 0) {
    if (colBase < HDIM) {                         // r-block: store bf16(r*h)
      #pragma unroll
      for (int mh = 0; mh < 2; ++mh)
        #pragma unroll
        for (int nh = 0; nh < 2; ++nh)
          #pragma unroll
          for (int mf = 0; mf < 2; ++mf)
            #pragma unroll
            for (int nf = 0; nf < 2; ++nf) {
              f32x4 v = acc[mh][nh][mf][nf];
              const int col = colBase + nh * 64 + wn * 32 + nf * 16 + lr;
              #pragma unroll
              for (int rr = 0; rr < 4; ++rr) {
                const int row = rowBase + mh * 64 + wm * 32 + mf * 16 + lkq * 4 + rr;
                const float sg = 1.f / (1.f + __expf(-v[rr]));
                const float hv = bf2f(hb[(size_t)row * KDIM + IDIM + col]);
                A2w[(size_t)row * KDIM + IDIM + col] = f2bf(sg * hv);
              }
            }
    } else {                                      // z-block: store bf16(1-z)
      #pragma unroll
      for (int mh = 0; mh < 2; ++mh)
        #pragma unroll
        for (int nh = 0; nh < 2; ++nh)
          #pragma unroll
          for (int mf = 0; mf < 2; ++mf)
            #pragma unroll
            for (int nf = 0; nf < 2; ++nf) {
              f32x4 v = acc[mh][nh][mf][nf];
              const int col = colBase - HDIM + nh * 64 + wn * 32 + nf * 16 + lr;
              #pragma unroll
              for (int rr = 0; rr < 4; ++rr) {
                const int row = rowBase + mh * 64 + wm * 32 + mf * 16 + lkq * 4 + rr;
                const float sg = 1.f / (1.f + __expf(-v[rr]));
                omz[(size_t)row * HDIM + col] = f2bf(1.f - sg);
              }
            }
    }
  } else {
    #pragma unroll
    for (int mh = 0; mh < 2; ++mh)
      #pragma unroll
      for (int nh = 0; nh < 2; ++nh)
        #pragma unroll
        for (int mf = 0; mf < 2; ++mf)
          #pragma unroll
          for (int nf = 0; nf < 2; ++nf) {
            f32x4 v = acc[mh][nh][mf][nf];
            const int col = colBase + nh * 64 + wn * 32 + nf * 16 + lr;
            #pragma unroll
            for (int rr = 0; rr < 4; ++rr) {
              const int row = rowBase + mh * 64 + wm * 32 + mf * 16 + lkq * 4 + rr;
              const float e  = __expf(2.f * v[rr]);
              const float ht = 1.f - 2.f / (e + 1.f);
              const float o  = bf2f(omz[(size_t)row * HDIM + col]);
              const float hv = bf2f(hb[(size_t)row * KDIM + IDIM + col]);
              out[(size_t)row * HDIM + col] = o * (ht - hv);
            }
          }
  }
}

// ---------------------------------------------------------------------------
extern "C" void kernel_launch(void* const* d_in, const int* in_sizes, int n_in,
                              void* d_out, int out_size, void* d_ws, size_t ws_size,
                              hipStream_t stream) {
  const float* t  = (const float*)d_in[0];
  const float* h  = (const float*)d_in[1];
  const float* xc = (const float*)d_in[2];
  const float* Wr = (const float*)d_in[3];
  const float* Wz = (const float*)d_in[4];
  const float* Wh = (const float*)d_in[5];
  float* out = (float*)d_out;

  u16* WB  = (u16*)d_ws;
  u16* A1  = WB + (size_t)3 * 1024 * KDIM;
  u16* A2  = A1 + (size_t)B_ROWS * KDIM;
  u16* omz = A2 + (size_t)B_ROWS * KDIM;

  convert_kernel<<<CV_BLOCKS, 256, 0, stream>>>(t, h, xc, Wr, Wz, Wh, WB, A1, A2);

  // GEMM1: [x|h] x [W_r;W_z]^T -> r,z ; grid 64x16 = 1024, 2 blocks/CU
  gemm128<0, 2048><<<1024, 256, 0, stream>>>(A1, WB, A1, A2, omz, out);

  // GEMM2: [x|r*h] x W_h^T -> htilde ; grid 64x8 = 512, 2 blocks/CU
  gemm128<1, 1024><<<512, 256, 0, stream>>>(A2, WB + (size_t)2048 * KDIM,
                                            A1, nullptr, omz, out);
}